// Round 1
// baseline (917.895 us; speedup 1.0000x reference)
//
#include <hip/hip_runtime.h>
#include <cstddef>
#include <cstdint>

#define B_ 32
#define N_ 8192
#define D_ 64
#define H_ 128
#define S_ 16
#define TAU_INV 10.0f

__device__ __forceinline__ float gelu_exact(float x){
    return 0.5f * x * (1.0f + erff(x * 0.70710678118654752f));
}

// ---------------------------------------------------------------------------
// Kernel A: feats = LN2( gelu(LN1(x@w1+b1)) @ w2 + b2 )   [B*N rows]
// 64 rows per block, 256 threads, per-thread 4 rows x 8 cols fp32 accumulators.
// ---------------------------------------------------------------------------
__global__ __launch_bounds__(256) void feats_kernel(
    const float* __restrict__ x, const float* __restrict__ w1, const float* __restrict__ b1,
    const float* __restrict__ ln1g, const float* __restrict__ ln1b,
    const float* __restrict__ w2g, const float* __restrict__ b2,
    const float* __restrict__ ln2g, const float* __restrict__ ln2b,
    float* __restrict__ feats)
{
    __shared__ float smem[12544];          // 50176 B
    float* xs  = smem;                     // [64][68]   phase 0/1
    float* w1s = smem + 4352;              // [64][128]  phase 0/1
    float* hs  = smem;                     // [64][132]  phase 1b/2 (aliases xs+w1s head)
    float* w2s = smem + 8448;              // [32][128]  phase 2 chunk

    const int tid  = threadIdx.x;
    const int row0 = blockIdx.x * 64;
    const int c0   = (tid & 15) * 8;
    const int r0   = (tid >> 4) * 4;

    // stage x tile (row-major, stride 68) and w1
    for (int i = tid; i < 1024; i += 256){
        int r = i >> 4, c4 = i & 15;
        float4 v = *(const float4*)(x + (size_t)(row0 + r) * 64 + c4 * 4);
        *(float4*)(xs + r * 68 + c4 * 4) = v;
    }
    for (int i = tid; i < 2048; i += 256)
        ((float4*)w1s)[i] = ((const float4*)w1)[i];
    __syncthreads();

    // phase 1: t = x@w1
    float acc[4][8];
    #pragma unroll
    for (int i=0;i<4;++i){
        #pragma unroll
        for (int j=0;j<8;++j) acc[i][j]=0.f;
    }
    #pragma unroll 4
    for (int d = 0; d < 64; ++d){
        float4 bv0 = *(const float4*)(w1s + d*128 + c0);
        float4 bv1 = *(const float4*)(w1s + d*128 + c0 + 4);
        float bv[8] = {bv0.x,bv0.y,bv0.z,bv0.w,bv1.x,bv1.y,bv1.z,bv1.w};
        float av[4];
        #pragma unroll
        for (int i=0;i<4;++i) av[i] = xs[(r0+i)*68 + d];
        #pragma unroll
        for (int i=0;i<4;++i){
            #pragma unroll
            for (int j=0;j<8;++j) acc[i][j] += av[i]*bv[j];
        }
    }

    // LN1 + gelu
    float4 bb0 = *(const float4*)(b1 + c0),   bb1 = *(const float4*)(b1 + c0 + 4);
    float4 gg0 = *(const float4*)(ln1g + c0), gg1 = *(const float4*)(ln1g + c0 + 4);
    float4 be0 = *(const float4*)(ln1b + c0), be1 = *(const float4*)(ln1b + c0 + 4);
    float bia[8] = {bb0.x,bb0.y,bb0.z,bb0.w,bb1.x,bb1.y,bb1.z,bb1.w};
    float gam[8] = {gg0.x,gg0.y,gg0.z,gg0.w,gg1.x,gg1.y,gg1.z,gg1.w};
    float bet[8] = {be0.x,be0.y,be0.z,be0.w,be1.x,be1.y,be1.z,be1.w};

    float hrow[4][8];
    #pragma unroll
    for (int i=0;i<4;++i){
        float v[8]; float s1=0.f, sq=0.f;
        #pragma unroll
        for (int j=0;j<8;++j){ v[j] = acc[i][j] + bia[j]; s1 += v[j]; sq += v[j]*v[j]; }
        #pragma unroll
        for (int m=1; m<16; m<<=1){ s1 += __shfl_xor(s1, m); sq += __shfl_xor(sq, m); }
        float mean = s1 * (1.0f/128.0f);
        float var  = sq * (1.0f/128.0f) - mean*mean;
        float rs   = 1.0f / sqrtf(var + 1e-5f);
        #pragma unroll
        for (int j=0;j<8;++j){
            float t = (v[j]-mean)*rs*gam[j] + bet[j];
            hrow[i][j] = gelu_exact(t);
        }
    }
    __syncthreads();                        // xs/w1s dead
    #pragma unroll
    for (int i=0;i<4;++i){
        *(float4*)(hs + (r0+i)*132 + c0)     = make_float4(hrow[i][0],hrow[i][1],hrow[i][2],hrow[i][3]);
        *(float4*)(hs + (r0+i)*132 + c0 + 4) = make_float4(hrow[i][4],hrow[i][5],hrow[i][6],hrow[i][7]);
    }

    // phase 2: u = h@w2 in 4 k-chunks of 32
    float acc2[4][8];
    #pragma unroll
    for (int i=0;i<4;++i){
        #pragma unroll
        for (int j=0;j<8;++j) acc2[i][j]=0.f;
    }
    for (int ck = 0; ck < 4; ++ck){
        __syncthreads();
        for (int i = tid; i < 1024; i += 256)
            ((float4*)w2s)[i] = ((const float4*)w2g)[ck*1024 + i];
        __syncthreads();
        #pragma unroll 4
        for (int k=0;k<32;++k){
            float4 bv0 = *(const float4*)(w2s + k*128 + c0);
            float4 bv1 = *(const float4*)(w2s + k*128 + c0 + 4);
            float bv[8] = {bv0.x,bv0.y,bv0.z,bv0.w,bv1.x,bv1.y,bv1.z,bv1.w};
            int kk = ck*32 + k;
            float av[4];
            #pragma unroll
            for (int i=0;i<4;++i) av[i] = hs[(r0+i)*132 + kk];
            #pragma unroll
            for (int i=0;i<4;++i){
                #pragma unroll
                for (int j=0;j<8;++j) acc2[i][j] += av[i]*bv[j];
            }
        }
    }

    // LN2 + store feats
    float4 cb0 = *(const float4*)(b2 + c0),   cb1 = *(const float4*)(b2 + c0 + 4);
    float4 cg0 = *(const float4*)(ln2g + c0), cg1 = *(const float4*)(ln2g + c0 + 4);
    float4 ce0 = *(const float4*)(ln2b + c0), ce1 = *(const float4*)(ln2b + c0 + 4);
    float bia2[8] = {cb0.x,cb0.y,cb0.z,cb0.w,cb1.x,cb1.y,cb1.z,cb1.w};
    float gam2[8] = {cg0.x,cg0.y,cg0.z,cg0.w,cg1.x,cg1.y,cg1.z,cg1.w};
    float bet2[8] = {ce0.x,ce0.y,ce0.z,ce0.w,ce1.x,ce1.y,ce1.z,ce1.w};

    #pragma unroll
    for (int i=0;i<4;++i){
        float v[8]; float s1=0.f, sq=0.f;
        #pragma unroll
        for (int j=0;j<8;++j){ v[j] = acc2[i][j] + bia2[j]; s1 += v[j]; sq += v[j]*v[j]; }
        #pragma unroll
        for (int m=1; m<16; m<<=1){ s1 += __shfl_xor(s1, m); sq += __shfl_xor(sq, m); }
        float mean = s1 * (1.0f/128.0f);
        float var  = sq * (1.0f/128.0f) - mean*mean;
        float rs   = 1.0f / sqrtf(var + 1e-5f);
        float o[8];
        #pragma unroll
        for (int j=0;j<8;++j) o[j] = (v[j]-mean)*rs*gam2[j] + bet2[j];
        float* dst = feats + (size_t)(row0 + r0 + i)*128 + c0;
        *(float4*)(dst)     = make_float4(o[0],o[1],o[2],o[3]);
        *(float4*)(dst + 4) = make_float4(o[4],o[5],o[6],o[7]);
    }
}

// ---------------------------------------------------------------------------
// init slots = broadcast slot_mu over batch
// ---------------------------------------------------------------------------
__global__ void init_slots(const float* __restrict__ mu, float* __restrict__ slots){
    int i = blockIdx.x * 256 + threadIdx.x;   // 65536 total
    slots[i] = mu[i & 2047];
}

// ---------------------------------------------------------------------------
// Kernel B: one attention iteration, fused.
// Per n (one wave): logit_s = (2*slot_s.f - |slot_s|^2)/tau  (f2 cancels in
// softmax over s); attn = softmax_s; accumulate num[s][h] += attn*f, den[s].
// lane = (s = l&15, ch = l>>4 -> 32-dim h-chunk). slots in registers.
// ---------------------------------------------------------------------------
__global__ __launch_bounds__(256) void attn_kernel(
    const float* __restrict__ feats, const float* __restrict__ slots,
    float* __restrict__ num, float* __restrict__ den,
    float* __restrict__ attn_out, const int write_attn)
{
    __shared__ float red[16*129 + 16];
    const int tid = threadIdx.x;
    const int b   = blockIdx.x >> 5;
    const int n0  = (blockIdx.x & 31) * 256;
    const int w   = tid >> 6;
    const int l   = tid & 63;
    const int s   = l & 15;
    const int ch  = l >> 4;

    for (int i = tid; i < 16*129+16; i += 256) red[i] = 0.f;

    float sreg[32];
    {
        const float* sp = slots + ((size_t)(b*16 + s))*128 + ch*32;
        #pragma unroll
        for (int j=0;j<8;++j){
            float4 v = ((const float4*)sp)[j];
            sreg[4*j]=v.x; sreg[4*j+1]=v.y; sreg[4*j+2]=v.z; sreg[4*j+3]=v.w;
        }
    }
    float s2p = 0.f;
    #pragma unroll
    for (int j=0;j<32;++j) s2p += sreg[j]*sreg[j];
    s2p += __shfl_xor(s2p, 16);
    s2p += __shfl_xor(s2p, 32);
    const float s2 = s2p;

    float numl[32];
    #pragma unroll
    for (int j=0;j<32;++j) numl[j]=0.f;
    float denl = 0.f;

    const float* fb = feats + ((size_t)b*N_ + n0)*128 + ch*32;
    const size_t attn_base = ((size_t)(b*16 + s))*N_ + n0;

    auto loadf = [&](float* dst, const float* src){
        #pragma unroll
        for (int j=0;j<8;++j){
            float4 v = ((const float4*)src)[j];
            dst[4*j]=v.x; dst[4*j+1]=v.y; dst[4*j+2]=v.z; dst[4*j+3]=v.w;
        }
    };
    auto process = [&](const float* f, int n){
        float d = 0.f;
        #pragma unroll
        for (int j=0;j<32;++j) d += sreg[j]*f[j];
        d += __shfl_xor(d, 16);
        d += __shfl_xor(d, 32);
        float logit = (2.f*d - s2) * TAU_INV;
        float m = logit;
        #pragma unroll
        for (int mk=1; mk<16; mk<<=1) m = fmaxf(m, __shfl_xor(m, mk));
        float e = expf(logit - m);
        float sum = e;
        #pragma unroll
        for (int mk=1; mk<16; mk<<=1) sum += __shfl_xor(sum, mk);
        float a = e / sum;
        #pragma unroll
        for (int j=0;j<32;++j) numl[j] += a * f[j];
        if (ch == 0){
            denl += a;
            if (write_attn) attn_out[attn_base + n] = a;
        }
    };

    float fA[32], fB[32];
    loadf(fA, fb + (size_t)w*128);
    for (int k2 = 0; k2 < 32; ++k2){
        int na = 8*k2 + w;
        loadf(fB, fb + (size_t)(na+4)*128);
        process(fA, na);
        if (k2 < 31) loadf(fA, fb + (size_t)(na+8)*128);
        process(fB, na+4);
    }

    __syncthreads();
    #pragma unroll
    for (int j=0;j<32;++j) atomicAdd(&red[s*129 + ch*32 + j], numl[j]);
    if (ch == 0) atomicAdd(&red[16*129 + s], denl);
    __syncthreads();
    for (int i = tid; i < 2048; i += 256){
        int ss = i >> 7, hh = i & 127;
        atomicAdd(&num[((size_t)b*16 + ss)*128 + hh], red[ss*129 + hh]);
    }
    if (tid < 16) atomicAdd(&den[b*16 + tid], red[16*129 + tid]);
}

// ---------------------------------------------------------------------------
// Kernel C: slot update (GRU + LN + MLP), 4 (b,s) rows per block.
// ---------------------------------------------------------------------------
__global__ __launch_bounds__(256) void update_kernel(
    const float* __restrict__ num, const float* __restrict__ den,
    float* __restrict__ slots,
    const float* __restrict__ gwi, const float* __restrict__ gwh,
    const float* __restrict__ gbi, const float* __restrict__ gbh,
    const float* __restrict__ mw1, const float* __restrict__ mb1,
    const float* __restrict__ mw2, const float* __restrict__ mb2,
    const float* __restrict__ ng, const float* __restrict__ nbv,
    float* __restrict__ out_slots, const int write_out)
{
    __shared__ float us[512], sl[512], gbuf[3072], nbuf[512], lnb[512], qb[512];
    const int tid  = threadIdx.x;
    const int row0 = blockIdx.x * 4;

    for (int i = tid; i < 512; i += 256){
        int r = i >> 7, h = i & 127;
        int grow = row0 + r;
        float dv = den[grow] + 1e-8f;
        us[i] = num[(size_t)grow*128 + h] / dv;
        sl[i] = slots[(size_t)grow*128 + h];
    }
    __syncthreads();

    // gi (which=0, from updates) and gh (which=1, from slots): 2*4*384 dots
    for (int idx = tid; idx < 3072; idx += 256){
        int which = idx >= 1536;
        int rem   = idx - which*1536;
        int r     = rem / 384;
        int o     = rem - r*384;
        const float* W   = which ? gwh : gwi;
        const float* bb  = which ? gbh : gbi;
        const float* src = (which ? sl : us) + r*128;
        float a = bb[o];
        const float4* Wr = (const float4*)(W + (size_t)o*128);
        #pragma unroll 8
        for (int k4=0;k4<32;++k4){
            float4 wv = Wr[k4];
            float4 sv = *(const float4*)(src + 4*k4);
            a += sv.x*wv.x + sv.y*wv.y + sv.z*wv.z + sv.w*wv.w;
        }
        gbuf[idx] = a;
    }
    __syncthreads();

    // gates (PyTorch order r,z,n)
    for (int i = tid; i < 512; i += 256){
        int r = i >> 7, h = i & 127;
        float ir  = gbuf[r*384 + h];
        float iz  = gbuf[r*384 + 128 + h];
        float in_ = gbuf[r*384 + 256 + h];
        float hr  = gbuf[1536 + r*384 + h];
        float hz  = gbuf[1536 + r*384 + 128 + h];
        float hn  = gbuf[1536 + r*384 + 256 + h];
        float rg = 1.f/(1.f + expf(-(ir+hr)));
        float zg = 1.f/(1.f + expf(-(iz+hz)));
        float nn = tanhf(in_ + rg*hn);
        nbuf[i] = (1.f - zg)*nn + zg*sl[i];
    }
    __syncthreads();

    // LN(new): wave w handles row w
    {
        int wv = tid >> 6, ll = tid & 63;
        float v0 = nbuf[wv*128 + ll], v1 = nbuf[wv*128 + 64 + ll];
        float s1 = v0 + v1, sq = v0*v0 + v1*v1;
        #pragma unroll
        for (int m=1; m<64; m<<=1){ s1 += __shfl_xor(s1,m); sq += __shfl_xor(sq,m); }
        float mean = s1*(1.f/128.f), var = sq*(1.f/128.f) - mean*mean;
        float rs = 1.f/sqrtf(var + 1e-5f);
        lnb[wv*128 + ll]      = (v0-mean)*rs*ng[ll] + nbv[ll];
        lnb[wv*128 + 64 + ll] = (v1-mean)*rs*ng[64+ll] + nbv[64+ll];
    }
    __syncthreads();

    // mlp1 + gelu
    for (int i = tid; i < 512; i += 256){
        int r = i >> 7, o = i & 127;
        float a = mb1[o];
        const float* lr = lnb + r*128;
        #pragma unroll 8
        for (int k=0;k<128;++k) a += lr[k] * mw1[(size_t)k*128 + o];
        qb[i] = gelu_exact(a);
    }
    __syncthreads();

    // mlp2 + residual, write slots (and d_out on last iter)
    for (int i = tid; i < 512; i += 256){
        int r = i >> 7, h = i & 127;
        float a = mb2[h];
        const float* qr = qb + r*128;
        #pragma unroll 8
        for (int k=0;k<128;++k) a += qr[k] * mw2[(size_t)k*128 + h];
        float ov = nbuf[i] + 0.2f*a;
        int grow = row0 + r;
        slots[(size_t)grow*128 + h] = ov;
        if (write_out) out_slots[(size_t)grow*128 + h] = ov;
    }
}

// ---------------------------------------------------------------------------
extern "C" void kernel_launch(void* const* d_in, const int* in_sizes, int n_in,
                              void* d_out, int out_size, void* d_ws, size_t ws_size,
                              hipStream_t stream)
{
    const float* x    = (const float*)d_in[0];
    const float* w1   = (const float*)d_in[1];
    const float* b1   = (const float*)d_in[2];
    const float* ln1g = (const float*)d_in[3];
    const float* ln1b = (const float*)d_in[4];
    const float* w2   = (const float*)d_in[5];
    const float* b2   = (const float*)d_in[6];
    const float* ln2g = (const float*)d_in[7];
    const float* ln2b = (const float*)d_in[8];
    const float* smu  = (const float*)d_in[9];
    const float* gwi  = (const float*)d_in[10];
    const float* gwh  = (const float*)d_in[11];
    const float* gbi  = (const float*)d_in[12];
    const float* gbh  = (const float*)d_in[13];
    const float* mw1  = (const float*)d_in[14];
    const float* mb1  = (const float*)d_in[15];
    const float* mw2  = (const float*)d_in[16];
    const float* mb2  = (const float*)d_in[17];
    const float* ng   = (const float*)d_in[18];
    const float* nbv  = (const float*)d_in[19];

    float* out_slots = (float*)d_out;
    float* out_attn  = (float*)d_out + (size_t)B_*S_*H_;

    float* feats = (float*)d_ws;                       // 32*8192*128 fp32 = 128 MB
    float* slots = feats + (size_t)B_*N_*H_;           // 65536
    float* num   = slots + B_*S_*H_;                   // 65536
    float* den   = num + B_*S_*H_;                     // 512

    feats_kernel<<<dim3(4096), dim3(256), 0, stream>>>(
        x, w1, b1, ln1g, ln1b, w2, b2, ln2g, ln2b, feats);
    init_slots<<<dim3(256), dim3(256), 0, stream>>>(smu, slots);

    for (int it = 0; it < 3; ++it){
        hipMemsetAsync(num, 0, (size_t)(B_*S_*H_ + B_*S_)*sizeof(float), stream);
        attn_kernel<<<dim3(1024), dim3(256), 0, stream>>>(
            feats, slots, num, den, out_attn, (it==2) ? 1 : 0);
        update_kernel<<<dim3(128), dim3(256), 0, stream>>>(
            num, den, slots, gwi, gwh, gbi, gbh, mw1, mb1, mw2, mb2, ng, nbv,
            out_slots, (it==2) ? 1 : 0);
    }
}

// Round 2
// 867.249 us; speedup vs baseline: 1.0584x; 1.0584x over previous
//
#include <hip/hip_runtime.h>
#include <cstddef>
#include <cstdint>

#define B_ 32
#define N_ 8192
#define D_ 64
#define H_ 128
#define S_ 16
// softmax computed in exp2 domain: logit_e2 = (2*dot - |s|^2) * 10 * log2(e)
#define L2SCALE 14.426950408889634f

__device__ __forceinline__ float gelu_exact(float x){
    return 0.5f * x * (1.0f + erff(x * 0.70710678118654752f));
}
__device__ __forceinline__ float dot4(float4 a, float4 b){
    return a.x*b.x + a.y*b.y + a.z*b.z + a.w*b.w;
}

// ---------------------------------------------------------------------------
// Kernel A: feats = LN2( gelu(LN1(x@w1+b1)) @ w2 + b2 )   [B*N rows]
// (unchanged from R1)
// ---------------------------------------------------------------------------
__global__ __launch_bounds__(256) void feats_kernel(
    const float* __restrict__ x, const float* __restrict__ w1, const float* __restrict__ b1,
    const float* __restrict__ ln1g, const float* __restrict__ ln1b,
    const float* __restrict__ w2g, const float* __restrict__ b2,
    const float* __restrict__ ln2g, const float* __restrict__ ln2b,
    float* __restrict__ feats)
{
    __shared__ float smem[12544];
    float* xs  = smem;                     // [64][68]
    float* w1s = smem + 4352;              // [64][128]
    float* hs  = smem;                     // [64][132]
    float* w2s = smem + 8448;              // [32][128]

    const int tid  = threadIdx.x;
    const int row0 = blockIdx.x * 64;
    const int c0   = (tid & 15) * 8;
    const int r0   = (tid >> 4) * 4;

    for (int i = tid; i < 1024; i += 256){
        int r = i >> 4, c4 = i & 15;
        float4 v = *(const float4*)(x + (size_t)(row0 + r) * 64 + c4 * 4);
        *(float4*)(xs + r * 68 + c4 * 4) = v;
    }
    for (int i = tid; i < 2048; i += 256)
        ((float4*)w1s)[i] = ((const float4*)w1)[i];
    __syncthreads();

    float acc[4][8];
    #pragma unroll
    for (int i=0;i<4;++i){
        #pragma unroll
        for (int j=0;j<8;++j) acc[i][j]=0.f;
    }
    #pragma unroll 4
    for (int d = 0; d < 64; ++d){
        float4 bv0 = *(const float4*)(w1s + d*128 + c0);
        float4 bv1 = *(const float4*)(w1s + d*128 + c0 + 4);
        float bv[8] = {bv0.x,bv0.y,bv0.z,bv0.w,bv1.x,bv1.y,bv1.z,bv1.w};
        float av[4];
        #pragma unroll
        for (int i=0;i<4;++i) av[i] = xs[(r0+i)*68 + d];
        #pragma unroll
        for (int i=0;i<4;++i){
            #pragma unroll
            for (int j=0;j<8;++j) acc[i][j] += av[i]*bv[j];
        }
    }

    float4 bb0 = *(const float4*)(b1 + c0),   bb1 = *(const float4*)(b1 + c0 + 4);
    float4 gg0 = *(const float4*)(ln1g + c0), gg1 = *(const float4*)(ln1g + c0 + 4);
    float4 be0 = *(const float4*)(ln1b + c0), be1 = *(const float4*)(ln1b + c0 + 4);
    float bia[8] = {bb0.x,bb0.y,bb0.z,bb0.w,bb1.x,bb1.y,bb1.z,bb1.w};
    float gam[8] = {gg0.x,gg0.y,gg0.z,gg0.w,gg1.x,gg1.y,gg1.z,gg1.w};
    float bet[8] = {be0.x,be0.y,be0.z,be0.w,be1.x,be1.y,be1.z,be1.w};

    float hrow[4][8];
    #pragma unroll
    for (int i=0;i<4;++i){
        float v[8]; float s1=0.f, sq=0.f;
        #pragma unroll
        for (int j=0;j<8;++j){ v[j] = acc[i][j] + bia[j]; s1 += v[j]; sq += v[j]*v[j]; }
        #pragma unroll
        for (int m=1; m<16; m<<=1){ s1 += __shfl_xor(s1, m); sq += __shfl_xor(sq, m); }
        float mean = s1 * (1.0f/128.0f);
        float var  = sq * (1.0f/128.0f) - mean*mean;
        float rs   = 1.0f / sqrtf(var + 1e-5f);
        #pragma unroll
        for (int j=0;j<8;++j){
            float t = (v[j]-mean)*rs*gam[j] + bet[j];
            hrow[i][j] = gelu_exact(t);
        }
    }
    __syncthreads();
    #pragma unroll
    for (int i=0;i<4;++i){
        *(float4*)(hs + (r0+i)*132 + c0)     = make_float4(hrow[i][0],hrow[i][1],hrow[i][2],hrow[i][3]);
        *(float4*)(hs + (r0+i)*132 + c0 + 4) = make_float4(hrow[i][4],hrow[i][5],hrow[i][6],hrow[i][7]);
    }

    float acc2[4][8];
    #pragma unroll
    for (int i=0;i<4;++i){
        #pragma unroll
        for (int j=0;j<8;++j) acc2[i][j]=0.f;
    }
    for (int ck = 0; ck < 4; ++ck){
        __syncthreads();
        for (int i = tid; i < 1024; i += 256)
            ((float4*)w2s)[i] = ((const float4*)w2g)[ck*1024 + i];
        __syncthreads();
        #pragma unroll 4
        for (int k=0;k<32;++k){
            float4 bv0 = *(const float4*)(w2s + k*128 + c0);
            float4 bv1 = *(const float4*)(w2s + k*128 + c0 + 4);
            float bv[8] = {bv0.x,bv0.y,bv0.z,bv0.w,bv1.x,bv1.y,bv1.z,bv1.w};
            int kk = ck*32 + k;
            float av[4];
            #pragma unroll
            for (int i=0;i<4;++i) av[i] = hs[(r0+i)*132 + kk];
            #pragma unroll
            for (int i=0;i<4;++i){
                #pragma unroll
                for (int j=0;j<8;++j) acc2[i][j] += av[i]*bv[j];
            }
        }
    }

    float4 cb0 = *(const float4*)(b2 + c0),   cb1 = *(const float4*)(b2 + c0 + 4);
    float4 cg0 = *(const float4*)(ln2g + c0), cg1 = *(const float4*)(ln2g + c0 + 4);
    float4 ce0 = *(const float4*)(ln2b + c0), ce1 = *(const float4*)(ln2b + c0 + 4);
    float bia2[8] = {cb0.x,cb0.y,cb0.z,cb0.w,cb1.x,cb1.y,cb1.z,cb1.w};
    float gam2[8] = {cg0.x,cg0.y,cg0.z,cg0.w,cg1.x,cg1.y,cg1.z,cg1.w};
    float bet2[8] = {ce0.x,ce0.y,ce0.z,ce0.w,ce1.x,ce1.y,ce1.z,ce1.w};

    #pragma unroll
    for (int i=0;i<4;++i){
        float v[8]; float s1=0.f, sq=0.f;
        #pragma unroll
        for (int j=0;j<8;++j){ v[j] = acc2[i][j] + bia2[j]; s1 += v[j]; sq += v[j]*v[j]; }
        #pragma unroll
        for (int m=1; m<16; m<<=1){ s1 += __shfl_xor(s1, m); sq += __shfl_xor(sq, m); }
        float mean = s1 * (1.0f/128.0f);
        float var  = sq * (1.0f/128.0f) - mean*mean;
        float rs   = 1.0f / sqrtf(var + 1e-5f);
        float o[8];
        #pragma unroll
        for (int j=0;j<8;++j) o[j] = (v[j]-mean)*rs*gam2[j] + bet2[j];
        float* dst = feats + (size_t)(row0 + r0 + i)*128 + c0;
        *(float4*)(dst)     = make_float4(o[0],o[1],o[2],o[3]);
        *(float4*)(dst + 4) = make_float4(o[4],o[5],o[6],o[7]);
    }
}

__global__ void init_slots(const float* __restrict__ mu, float* __restrict__ slots){
    int i = blockIdx.x * 256 + threadIdx.x;
    slots[i] = mu[i & 2047];
}

// ---------------------------------------------------------------------------
// Kernel B (v2): lane owns (slot-pair, 16-wide k/h chunk). Slots live in
// registers for the whole wave. Per n: 4 broadcast float4 loads, 32-FMA dot,
// 3+3+3 butterfly shuffles (dot / max / sum), 2 exp2, 32-FMA in-register
// num accumulation. f2 cancels in softmax over slots.
// ---------------------------------------------------------------------------
__global__ __launch_bounds__(256) void attn_kernel(
    const float* __restrict__ feats, const float* __restrict__ slots,
    float* __restrict__ num, float* __restrict__ den,
    float* __restrict__ attn_out, const int write_attn)
{
    __shared__ float num_red[16*129];
    __shared__ float den_red[16];
    __shared__ float a_buf[4][16*64];

    const int tid = threadIdx.x;
    const int w   = tid >> 6;
    const int l   = tid & 63;
    const int s2i = l & 7;          // slot-pair index
    const int kg  = l >> 3;         // 16-wide k/h chunk index
    const int sA  = s2i * 2, sB = sA + 1;
    const int b   = blockIdx.x >> 5;
    const int n0  = (blockIdx.x & 31) * 256 + w * 64;

    for (int i = tid; i < 16*129; i += 256) num_red[i] = 0.f;
    if (tid < 16) den_red[tid] = 0.f;
    __syncthreads();

    // slot fragments in registers (loaded once)
    float4 sa[4], sb[4];
    {
        const float4* pA = (const float4*)(slots + ((size_t)(b*16 + sA))*128 + kg*16);
        const float4* pB = (const float4*)(slots + ((size_t)(b*16 + sB))*128 + kg*16);
        #pragma unroll
        for (int j=0;j<4;++j){ sa[j] = pA[j]; sb[j] = pB[j]; }
    }
    // |slot|^2 via butterfly over kg
    float qA = 0.f, qB = 0.f;
    #pragma unroll
    for (int j=0;j<4;++j){ qA += dot4(sa[j],sa[j]); qB += dot4(sb[j],sb[j]); }
    #pragma unroll
    for (int m=8; m<64; m<<=1){ qA += __shfl_xor(qA,m); qB += __shfl_xor(qB,m); }

    float4 na[4], nb[4];
    #pragma unroll
    for (int j=0;j<4;++j){ na[j] = make_float4(0,0,0,0); nb[j] = make_float4(0,0,0,0); }
    float denA = 0.f, denB = 0.f;

    const float* frow = feats + ((size_t)b*N_ + n0)*128 + kg*16;

    float4 c0,c1,c2,c3, p0,p1,p2,p3;
    { const float4* fp = (const float4*)frow;
      c0=fp[0]; c1=fp[1]; c2=fp[2]; c3=fp[3]; }

    for (int i = 0; i < 64; ++i){
        if (i < 63){
            const float4* fp = (const float4*)(frow + (size_t)(i+1)*128);
            p0=fp[0]; p1=fp[1]; p2=fp[2]; p3=fp[3];
        }
        // dots (partial over this lane's 16 k)
        float dA = dot4(sa[0],c0) + dot4(sa[1],c1) + dot4(sa[2],c2) + dot4(sa[3],c3);
        float dB = dot4(sb[0],c0) + dot4(sb[1],c1) + dot4(sb[2],c2) + dot4(sb[3],c3);
        #pragma unroll
        for (int m=8; m<64; m<<=1){ dA += __shfl_xor(dA,m); dB += __shfl_xor(dB,m); }
        float LA = (2.f*dA - qA) * L2SCALE;
        float LB = (2.f*dB - qB) * L2SCALE;
        // global max over 16 slots
        float mx = fmaxf(LA, LB);
        #pragma unroll
        for (int m=1; m<8; m<<=1) mx = fmaxf(mx, __shfl_xor(mx,m));
        float eA = exp2f(LA - mx), eB = exp2f(LB - mx);
        float z = eA + eB;
        #pragma unroll
        for (int m=1; m<8; m<<=1) z += __shfl_xor(z,m);
        float rz = 1.f / z;
        float aA = eA * rz, aB = eB * rz;
        denA += aA; denB += aB;
        #pragma unroll
        for (int j=0;j<4;++j){
            float4 cv = (j==0)?c0:(j==1)?c1:(j==2)?c2:c3;
            na[j].x += aA*cv.x; na[j].y += aA*cv.y; na[j].z += aA*cv.z; na[j].w += aA*cv.w;
            nb[j].x += aB*cv.x; nb[j].y += aB*cv.y; nb[j].z += aB*cv.z; nb[j].w += aB*cv.w;
        }
        if (write_attn && kg == 0){
            a_buf[w][sA*64 + i] = aA;
            a_buf[w][sB*64 + i] = aB;
        }
        c0=p0; c1=p1; c2=p2; c3=p3;
    }

    // per-wave LDS reduce (amortized over 64 n)
    #pragma unroll
    for (int j=0;j<4;++j){
        const float* va = (const float*)&na[j];
        const float* vb = (const float*)&nb[j];
        #pragma unroll
        for (int cc=0; cc<4; ++cc){
            atomicAdd(&num_red[sA*129 + kg*16 + j*4 + cc], va[cc]);
            atomicAdd(&num_red[sB*129 + kg*16 + j*4 + cc], vb[cc]);
        }
    }
    if (kg == 0){
        atomicAdd(&den_red[sA], denA);
        atomicAdd(&den_red[sB], denB);
    }
    __syncthreads();

    for (int i = tid; i < 2048; i += 256){
        int ss = i >> 7, hh = i & 127;
        atomicAdd(&num[((size_t)b*16 + ss)*128 + hh], num_red[ss*129 + hh]);
    }
    if (tid < 16) atomicAdd(&den[b*16 + tid], den_red[tid]);

    if (write_attn){
        // wave-local coalesced copy of its 16x64 attn tile
        for (int t = l; t < 1024; t += 64){
            int ss = t >> 6, ii = t & 63;
            attn_out[((size_t)(b*16 + ss))*N_ + n0 + ii] = a_buf[w][t];
        }
    }
}

// ---------------------------------------------------------------------------
// Kernel C: slot update (GRU + LN + MLP), unchanged.
// ---------------------------------------------------------------------------
__global__ __launch_bounds__(256) void update_kernel(
    const float* __restrict__ num, const float* __restrict__ den,
    float* __restrict__ slots,
    const float* __restrict__ gwi, const float* __restrict__ gwh,
    const float* __restrict__ gbi, const float* __restrict__ gbh,
    const float* __restrict__ mw1, const float* __restrict__ mb1,
    const float* __restrict__ mw2, const float* __restrict__ mb2,
    const float* __restrict__ ng, const float* __restrict__ nbv,
    float* __restrict__ out_slots, const int write_out)
{
    __shared__ float us[512], sl[512], gbuf[3072], nbuf[512], lnb[512], qb[512];
    const int tid  = threadIdx.x;
    const int row0 = blockIdx.x * 4;

    for (int i = tid; i < 512; i += 256){
        int r = i >> 7, h = i & 127;
        int grow = row0 + r;
        float dv = den[grow] + 1e-8f;
        us[i] = num[(size_t)grow*128 + h] / dv;
        sl[i] = slots[(size_t)grow*128 + h];
    }
    __syncthreads();

    for (int idx = tid; idx < 3072; idx += 256){
        int which = idx >= 1536;
        int rem   = idx - which*1536;
        int r     = rem / 384;
        int o     = rem - r*384;
        const float* W   = which ? gwh : gwi;
        const float* bb  = which ? gbh : gbi;
        const float* src = (which ? sl : us) + r*128;
        float a = bb[o];
        const float4* Wr = (const float4*)(W + (size_t)o*128);
        #pragma unroll 8
        for (int k4=0;k4<32;++k4){
            float4 wv = Wr[k4];
            float4 sv = *(const float4*)(src + 4*k4);
            a += sv.x*wv.x + sv.y*wv.y + sv.z*wv.z + sv.w*wv.w;
        }
        gbuf[idx] = a;
    }
    __syncthreads();

    for (int i = tid; i < 512; i += 256){
        int r = i >> 7, h = i & 127;
        float ir  = gbuf[r*384 + h];
        float iz  = gbuf[r*384 + 128 + h];
        float in_ = gbuf[r*384 + 256 + h];
        float hr  = gbuf[1536 + r*384 + h];
        float hz  = gbuf[1536 + r*384 + 128 + h];
        float hn  = gbuf[1536 + r*384 + 256 + h];
        float rg = 1.f/(1.f + expf(-(ir+hr)));
        float zg = 1.f/(1.f + expf(-(iz+hz)));
        float nn = tanhf(in_ + rg*hn);
        nbuf[i] = (1.f - zg)*nn + zg*sl[i];
    }
    __syncthreads();

    {
        int wv = tid >> 6, ll = tid & 63;
        float v0 = nbuf[wv*128 + ll], v1 = nbuf[wv*128 + 64 + ll];
        float s1 = v0 + v1, sq = v0*v0 + v1*v1;
        #pragma unroll
        for (int m=1; m<64; m<<=1){ s1 += __shfl_xor(s1,m); sq += __shfl_xor(sq,m); }
        float mean = s1*(1.f/128.f), var = sq*(1.f/128.f) - mean*mean;
        float rs = 1.f/sqrtf(var + 1e-5f);
        lnb[wv*128 + ll]      = (v0-mean)*rs*ng[ll] + nbv[ll];
        lnb[wv*128 + 64 + ll] = (v1-mean)*rs*ng[64+ll] + nbv[64+ll];
    }
    __syncthreads();

    for (int i = tid; i < 512; i += 256){
        int r = i >> 7, o = i & 127;
        float a = mb1[o];
        const float* lr = lnb + r*128;
        #pragma unroll 8
        for (int k=0;k<128;++k) a += lr[k] * mw1[(size_t)k*128 + o];
        qb[i] = gelu_exact(a);
    }
    __syncthreads();

    for (int i = tid; i < 512; i += 256){
        int r = i >> 7, h = i & 127;
        float a = mb2[h];
        const float* qr = qb + r*128;
        #pragma unroll 8
        for (int k=0;k<128;++k) a += qr[k] * mw2[(size_t)k*128 + h];
        float ov = nbuf[i] + 0.2f*a;
        int grow = row0 + r;
        slots[(size_t)grow*128 + h] = ov;
        if (write_out) out_slots[(size_t)grow*128 + h] = ov;
    }
}

// ---------------------------------------------------------------------------
extern "C" void kernel_launch(void* const* d_in, const int* in_sizes, int n_in,
                              void* d_out, int out_size, void* d_ws, size_t ws_size,
                              hipStream_t stream)
{
    const float* x    = (const float*)d_in[0];
    const float* w1   = (const float*)d_in[1];
    const float* b1   = (const float*)d_in[2];
    const float* ln1g = (const float*)d_in[3];
    const float* ln1b = (const float*)d_in[4];
    const float* w2   = (const float*)d_in[5];
    const float* b2   = (const float*)d_in[6];
    const float* ln2g = (const float*)d_in[7];
    const float* ln2b = (const float*)d_in[8];
    const float* smu  = (const float*)d_in[9];
    const float* gwi  = (const float*)d_in[10];
    const float* gwh  = (const float*)d_in[11];
    const float* gbi  = (const float*)d_in[12];
    const float* gbh  = (const float*)d_in[13];
    const float* mw1  = (const float*)d_in[14];
    const float* mb1  = (const float*)d_in[15];
    const float* mw2  = (const float*)d_in[16];
    const float* mb2  = (const float*)d_in[17];
    const float* ng   = (const float*)d_in[18];
    const float* nbv  = (const float*)d_in[19];

    float* out_slots = (float*)d_out;
    float* out_attn  = (float*)d_out + (size_t)B_*S_*H_;

    float* feats = (float*)d_ws;
    float* slots = feats + (size_t)B_*N_*H_;
    float* num   = slots + B_*S_*H_;
    float* den   = num + B_*S_*H_;

    feats_kernel<<<dim3(4096), dim3(256), 0, stream>>>(
        x, w1, b1, ln1g, ln1b, w2, b2, ln2g, ln2b, feats);
    init_slots<<<dim3(256), dim3(256), 0, stream>>>(smu, slots);

    for (int it = 0; it < 3; ++it){
        hipMemsetAsync(num, 0, (size_t)(B_*S_*H_ + B_*S_)*sizeof(float), stream);
        attn_kernel<<<dim3(1024), dim3(256), 0, stream>>>(
            feats, slots, num, den, out_attn, (it==2) ? 1 : 0);
        update_kernel<<<dim3(128), dim3(256), 0, stream>>>(
            num, den, slots, gwi, gwh, gbi, gbh, mw1, mb1, mw2, mb2, ng, nbv,
            out_slots, (it==2) ? 1 : 0);
    }
}